// Round 17
// baseline (80.440 us; speedup 1.0000x reference)
//
#include <hip/hip_runtime.h>
#include <math.h>

// Problem constants
#define BB 2      // batch
#define NS 25     // support images
#define NQ 16     // queries
#define KW 5      // n_way
#define C  640
#define HW 25     // 5x5
#define C2 1280
#define P  160    // BB*NQ*KW

typedef unsigned short ushort_t;
typedef unsigned int uint_t;
typedef __attribute__((ext_vector_type(8))) short short8;
typedef __attribute__((ext_vector_type(4))) short short4v;
typedef __attribute__((ext_vector_type(16))) float f32x16;

// Workspace layout (float offsets)
#define WS_PROTO   0          // 160000
#define WS_WDH     160000     // 92160 (184320 ushort)
#define WS_WDL     252160     // 92160
#define WS_CW      344320     // 6400
#define WS_WMFH    351680     // 512000 (1.024M ushort)
#define WS_OFFP    863680     // P*16*450 = 1152000
#define WS_FILTP   2015680    // P*8*225 = 288000 -> end 2303680 (9.2MB)

static __device__ inline ushort_t f2bf(float x) {
    uint_t u = __float_as_uint(x);
    uint_t r = (u + 0x7FFFu + ((u >> 16) & 1u)) >> 16;
    return (ushort_t)r;
}
static __device__ inline float bf2f(ushort_t b) {
    return __uint_as_float(((uint_t)b) << 16);
}

// ---------------- fused prep (branch by block) --------------------------
// blocks 0..124:   proto — thread per (bi,c,hw); each sf value read ONCE,
//                  accumulated into all 5 class sums (bitwise-identical).
// blocks 125..624: w_off -> A-frags (hi only)
// blocks 625..714: w_def -> A-frags (hi/lo)
#define PB_PROTO 125
#define PB_WMF   500
#define PB_WDF   90
__global__ void k_prep(const float* __restrict__ sf, const float* __restrict__ st,
                       const float* __restrict__ w_off, const float* __restrict__ w_def,
                       float* __restrict__ proto, ushort_t* __restrict__ wh,
                       ushort_t* __restrict__ wdh, ushort_t* __restrict__ wdl) {
    int b = blockIdx.x;
    int tid = threadIdx.x;
    if (b < PB_PROTO) {
        __shared__ float stw[250];    // st is (bi,n,k) linear = bi*125+n*5+k
        if (tid < 250) stw[tid] = st[tid];
        __syncthreads();
        int i = b * 256 + tid;        // < 32000 exactly (125*256)
        int bi = i / 16000;
        int e = i - bi * 16000;       // c*25+hw
        const float* sfb = sf + (size_t)bi * NS * 16000 + e;
        int sb = bi * 125;
        float num0 = 0.f, num1 = 0.f, num2 = 0.f, num3 = 0.f, num4 = 0.f;
        float den0 = 0.f, den1 = 0.f, den2 = 0.f, den3 = 0.f, den4 = 0.f;
        for (int n = 0; n < NS; ++n) {
            float v = sfb[(size_t)n * 16000];
            const float* w = &stw[sb + n * 5];
            num0 = fmaf(w[0], v, num0); den0 += w[0];
            num1 = fmaf(w[1], v, num1); den1 += w[1];
            num2 = fmaf(w[2], v, num2); den2 += w[2];
            num3 = fmaf(w[3], v, num3); den3 += w[3];
            num4 = fmaf(w[4], v, num4); den4 += w[4];
        }
        float* pr = proto + (size_t)bi * 5 * 16000 + e;
        pr[0 * 16000] = num0 / den0;
        pr[1 * 16000] = num1 / den1;
        pr[2 * 16000] = num2 / den2;
        pr[3 * 16000] = num3 / den3;
        pr[4 * 16000] = num4 / den4;
    } else if (b < PB_PROTO + PB_WMF) {
        // layout [kc(16)][t(25)][c16(5)][lane(64)][j(8)] = idx*8+j
        // A-frag (32x32x16): row(o)=lane&31, k(c_local)=(lane>>5)*8+j
        int idx = (b - PB_PROTO) * 256 + tid;   // < 128000 exactly
        int lane = idx & 63;
        int r = idx >> 6;
        int c16 = r % 5; r /= 5;
        int t = r % 25;
        int kc = r / 25;
        int o = lane & 31;
        int cb = kc * 80 + c16 * 16 + ((lane >> 5) << 3);
        union { short8 v; ushort_t u[8]; } hs;
        #pragma unroll
        for (int j = 0; j < 8; ++j) {
            float w = (o < 18) ? w_off[((size_t)o * C2 + cb + j) * 25 + t] : 0.f;
            hs.u[j] = f2bf(w);
        }
        *(short8*)(wh + (size_t)idx * 8) = hs.v;
    } else {
        // layout [kc(8)][s(45)][lane(64)][j(8)]; k_lin=s*16+(lane>>5)*8+j
        int idx = (b - PB_PROTO - PB_WMF) * 256 + tid;
        if (idx >= 8 * 45 * 64) return;
        int lane = idx & 63;
        int r = idx >> 6;
        int s = r % 45;
        int kc = r / 45;
        int o = lane & 31;
        int kbase = s * 16 + ((lane >> 5) << 3);
        union { short8 v; ushort_t u[8]; } hs, ls;
        #pragma unroll
        for (int j = 0; j < 8; ++j) {
            int k_lin = kbase + j;
            int c_local = k_lin / 9, kk = k_lin - 9 * c_local;
            float w = (o < 9) ? w_def[((size_t)o * C + kc * 80 + c_local) * 9 + kk] : 0.f;
            ushort_t h = f2bf(w);
            hs.u[j] = h;
            ls.u[j] = f2bf(w - bf2f(h));
        }
        *(short8*)(wdh + (size_t)idx * 8) = hs.v;
        *(short8*)(wdl + (size_t)idx * 8) = ls.v;
    }
}

// ---------------- 5x5 offset conv (MFMA, 1 pass, 2 pairs) + normcw ------
// blocks 0..1279: k_off, g=b>>4 (2 pairs), kc=b&15 (80-ch K-chunk).
// blocks 1280..1289: fused norm+cw for (bi,k) = b-1280.
// Only row 0 (the OOB zero row) is ever read from unwritten space, so only
// that row is zeroed (92 dwords vs 2392).
__launch_bounds__(256)
__attribute__((amdgpu_waves_per_eu(4, 4)))
__global__ void k_off(const float* __restrict__ qf, const float* __restrict__ proto,
                      const ushort_t* __restrict__ wh, float* __restrict__ offp,
                      float* __restrict__ cw) {
    __shared__ __align__(16) float scr[4096];      // 16 KB; B0|B1 alias low 9568 B
    int tid = threadIdx.x;
    if (blockIdx.x >= 1280) {
        // ---- norm + cw for one (bi,k) ----
        float* nr = scr;            // [250]
        float* inv = scr + 256;     // [25]
        int blk = blockIdx.x - 1280;
        const float* base = proto + (size_t)blk * C * HW;
        if (tid < 250) {
            int hw = tid / 10, sl = tid % 10;
            float s = 0.f;
            for (int c = sl; c < C; c += 10) { float v = base[c * HW + hw]; s += v * v; }
            nr[tid] = s;
        }
        __syncthreads();
        if (tid < 25) {
            float s = 0.f;
            #pragma unroll
            for (int j = 0; j < 10; ++j) s += nr[tid * 10 + j];
            inv[tid] = 1.f / fmaxf(sqrtf(s), 1e-12f);
        }
        __syncthreads();
        for (int c = tid; c < C; c += 256) {
            float s = 0.f;
            #pragma unroll
            for (int hw = 0; hw < HW; ++hw) s += base[c * HW + hw] * inv[hw];
            cw[(size_t)blk * C + c] = s * (1.f / 25.f);
        }
        return;
    }
    ushort_t* B0 = (ushort_t*)scr;                 // [26][92]
    ushort_t* B1 = (ushort_t*)scr + 2392;
    int g = blockIdx.x >> 4, kc = blockIdx.x & 15;
    int cbase = kc * 80;
    int lane = tid & 63, wv = tid >> 6;

    // pair source pointers (qf-vs-proto choice is block-uniform)
    int p0 = g * 2, p1 = g * 2 + 1;
    int bi0 = p0 / (NQ * KW), rm0 = p0 % (NQ * KW);
    int bi1 = p1 / (NQ * KW), rm1 = p1 % (NQ * KW);
    const float* src0 = (cbase < C)
        ? qf + ((bi0 * NQ + rm0 / KW) * C + cbase) * HW
        : proto + ((bi0 * KW + rm0 % KW) * C + (cbase - C)) * HW;
    const float* src1 = (cbase < C)
        ? qf + ((bi1 * NQ + rm1 / KW) * C + cbase) * HW
        : proto + ((bi1 * KW + rm1 % KW) * C + (cbase - C)) * HW;

    // batched loads into registers (independent, one waitcnt)
    float v[16];
    #pragma unroll
    for (int r = 0; r < 16; ++r) {
        int i = tid + r * 256;
        int e = min(i, 3999);
        v[r] = (e < 2000) ? src0[e] : src1[e - 2000];
    }

    // zero only the OOB row (row 0 of each pair): 46 dwords each
    if (tid < 92) {
        int j = tid / 46, o = tid - j * 46;
        ((uint_t*)B0)[j * 1196 + o] = 0u;
    }
    __syncthreads();
    #pragma unroll
    for (int r = 0; r < 16; ++r) {
        int i = tid + r * 256;
        if (i < 4000) {
            int j = i / 2000, e = i % 2000;
            int cc = e / 25, pp = e % 25;
            (j ? B1 : B0)[(1 + pp) * 92 + cc] = f2bf(v[r]);
        }
    }
    __syncthreads();

    int hw = lane & 31;
    int by = hw / 5, bx = hw % 5;          // lanes hw>=25 compute junk, never read
    int laneCh = (lane >> 5) * 8;
    const ushort_t* whp = wh + (size_t)kc * 64000 + lane * 8;

    f32x16 acc0, acc1;
    #pragma unroll
    for (int r = 0; r < 16; ++r) { acc0[r] = 0.f; acc1[r] = 0.f; }

    union U8 { short8 v8; short4v v4[2]; };

    for (int t = wv; t < 25; t += 4) {
        int ty = t / 5, tx = t % 5;
        int ry = by + ty - 2, rx = bx + tx - 2;
        bool valid = (ry >= 0 && ry < 5 && rx >= 0 && rx < 5);
        int row = valid ? (1 + ry * 5 + rx) : 0;
        int base0 = row * 92 + laneCh;
        const ushort_t* ahp = whp + (size_t)t * 2560;
        #pragma unroll
        for (int c16 = 0; c16 < 5; ++c16) {
            short8 a_h = *(const short8*)(ahp + c16 * 512);
            U8 b0, b1;
            b0.v4[0] = *(const short4v*)(B0 + base0 + c16 * 16);
            b0.v4[1] = *(const short4v*)(B0 + base0 + c16 * 16 + 4);
            b1.v4[0] = *(const short4v*)(B1 + base0 + c16 * 16);
            b1.v4[1] = *(const short4v*)(B1 + base0 + c16 * 16 + 4);
            acc0 = __builtin_amdgcn_mfma_f32_32x32x16_bf16(a_h, b0.v8, acc0, 0, 0, 0);
            acc1 = __builtin_amdgcn_mfma_f32_32x32x16_bf16(a_h, b1.v8, acc1, 0, 0, 0);
        }
    }

    #define EMIT_PAIR(J, ACC)                                                   \
    {                                                                           \
        __syncthreads();                                                        \
        _Pragma("unroll")                                                       \
        for (int r = 0; r < 16; ++r) scr[r * 256 + tid] = ACC[r];               \
        __syncthreads();                                                        \
        int p = g * 2 + (J);                                                    \
        float* dst = offp + ((size_t)p * 16 + kc) * 450;                        \
        for (int i = tid; i < 450; i += 256) {                                  \
            int o = i / 25, hw2 = i % 25;                                       \
            int r = (o & 3) | ((o >> 3) << 2);                                  \
            int ln = hw2 + ((o >> 2) & 1) * 32;                                 \
            float s = scr[r * 256 + ln] + scr[r * 256 + 64 + ln]                \
                    + scr[r * 256 + 128 + ln] + scr[r * 256 + 192 + ln];        \
            dst[o * 25 + hw2] = s;                                              \
        }                                                                       \
    }
    EMIT_PAIR(0, acc0)
    EMIT_PAIR(1, acc1)
    #undef EMIT_PAIR
}

// ---------------- deformable 3x3 conv via MFMA, C-split 8 ---------------
__launch_bounds__(256)
__global__ void k_def(const float* __restrict__ proto, const float* __restrict__ offp,
                      const ushort_t* __restrict__ wdh, const ushort_t* __restrict__ wdl,
                      float* __restrict__ filtp) {
    __shared__ __align__(16) float plds[2000];        // [80 c][25 hw]
    __shared__ __align__(16) ushort_t samp[25 * 728]; // 36400 B; scr aliases
    int p = blockIdx.x, kc = blockIdx.y;
    int bi = p / (NQ * KW); int rem = p % (NQ * KW);
    int k = rem % KW;
    const float* ftr = proto + ((bi * KW + k) * C + kc * 80) * HW;
    int tid = threadIdx.x, lane = tid & 63, wv = tid >> 6;

    // register-batched staging of plds
    float pv[8];
    #pragma unroll
    for (int r = 0; r < 8; ++r) pv[r] = ftr[min(tid + r * 256, 1999)];
    #pragma unroll
    for (int r = 0; r < 8; ++r) {
        int i = tid + r * 256;
        if (i < 2000) plds[i] = pv[r];
    }
    __syncthreads();

    if (tid < 225) {
        int kk = tid / 25, hw = tid % 25;
        float offY = 0.f, offX = 0.f;
        #pragma unroll
        for (int kcc = 0; kcc < 16; ++kcc) {
            const float* ob = offp + ((size_t)p * 16 + kcc) * 450;
            offY += ob[(kk * 2 + 0) * 25 + hw];
            offX += ob[(kk * 2 + 1) * 25 + hw];
        }
        int h = hw / 5, w = hw % 5, ky = kk / 3, kx = kk % 3;
        float py = (float)(h + ky - 1) + offY;
        float px = (float)(w + kx - 1) + offX;
        float y0f = floorf(py), x0f = floorf(px);
        float ty = py - y0f, tx = px - x0f;
        int y0 = (int)y0f, x0 = (int)x0f;
        int y1 = y0 + 1, x1 = x0 + 1;
        bool vy0 = (y0 >= 0 && y0 < 5), vy1 = (y1 >= 0 && y1 < 5);
        bool vx0 = (x0 >= 0 && x0 < 5), vx1 = (x1 >= 0 && x1 < 5);
        int cy0 = min(max(y0, 0), 4), cy1 = min(max(y1, 0), 4);
        int cx0 = min(max(x0, 0), 4), cx1 = min(max(x1, 0), 4);
        int i0 = cy0 * 5 + cx0, i1 = cy0 * 5 + cx1;
        int i2 = cy1 * 5 + cx0, i3 = cy1 * 5 + cx1;
        float wb0 = (vy0 && vx0) ? (1.f - ty) * (1.f - tx) : 0.f;
        float wb1 = (vy0 && vx1) ? (1.f - ty) * tx : 0.f;
        float wb2 = (vy1 && vx0) ? ty * (1.f - tx) : 0.f;
        float wb3 = (vy1 && vx1) ? ty * tx : 0.f;
        for (int c = 0; c < 80; ++c) {
            const float* base = &plds[c * 25];
            float s = wb0 * base[i0] + wb1 * base[i1] + wb2 * base[i2] + wb3 * base[i3];
            samp[hw * 728 + c * 9 + kk] = f2bf(s);
        }
    }
    __syncthreads();

    int hwr = (lane & 31) < 25 ? (lane & 31) : 0;    // junk cols never read back
    int k8 = (lane >> 5) * 8;
    const ushort_t* ahp = wdh + ((size_t)kc * 45 * 64 + lane) * 8;
    const ushort_t* alp = wdl + ((size_t)kc * 45 * 64 + lane) * 8;

    f32x16 acc;
    #pragma unroll
    for (int r = 0; r < 16; ++r) acc[r] = 0.f;

    for (int s = wv; s < 45; s += 4) {
        short8 b = *(const short8*)(samp + hwr * 728 + s * 16 + k8);
        short8 a_l = *(const short8*)(alp + (size_t)s * 512);
        short8 a_h = *(const short8*)(ahp + (size_t)s * 512);
        acc = __builtin_amdgcn_mfma_f32_32x32x16_bf16(a_l, b, acc, 0, 0, 0);
        acc = __builtin_amdgcn_mfma_f32_32x32x16_bf16(a_h, b, acc, 0, 0, 0);
    }

    __syncthreads();
    float* scr = (float*)samp;    // 16 KB <= 36.4 KB
    #pragma unroll
    for (int r = 0; r < 16; ++r) scr[r * 256 + tid] = acc[r];
    __syncthreads();

    float* dst = filtp + ((size_t)p * 8 + kc) * 225;
    for (int i = tid; i < 225; i += 256) {
        int o = i / 25, hw2 = i % 25;
        int r = (o & 3) | ((o >> 3) << 2);
        int ln = hw2 + ((o >> 2) & 1) * 32;
        float s = scr[r * 256 + ln] + scr[r * 256 + 64 + ln]
                + scr[r * 256 + 128 + ln] + scr[r * 256 + 192 + ln];
        dst[o * 25 + hw2] = s;
    }
}

// ---------------- RK4 + class score, one block per p (no k_fin) ---------
// 128 threads; ch-loop (rolled) covers the 5 channel chunks; filtp
// reduction + sigmoid + fl staging done ONCE per p (was 5x); out written
// directly. No atomics/fences (the 21us lesson from R11/R13/R15).
#define GSTEP(QA, KA)                                                       \
    {                                                                       \
        _Pragma("unroll")                                                   \
        for (int hw_ = 0; hw_ < 25; ++hw_) {                                \
            const int h_ = hw_ / 5, w_ = hw_ % 5;                           \
            float4 fA_ = *(const float4*)&fl[hw_ * 12];                     \
            float4 fB_ = *(const float4*)&fl[hw_ * 12 + 4];                 \
            float f8_ = fl[hw_ * 12 + 8];                                   \
            const float flv_[9] = {fA_.x, fA_.y, fA_.z, fA_.w,              \
                                   fB_.x, fB_.y, fB_.z, fB_.w, f8_};        \
            float s_ = 0.f;                                                 \
            _Pragma("unroll")                                               \
            for (int kp_ = 0; kp_ < 9; ++kp_) {                             \
                const int y_ = h_ + kp_ / 3 - 1, x_ = w_ + kp_ % 3 - 1;     \
                if (y_ >= 0 && y_ < 5 && x_ >= 0 && x_ < 5)                 \
                    s_ = fmaf(QA[y_ * 5 + x_], flv_[kp_], s_);              \
            }                                                               \
            KA[hw_] = fmaxf(s_, 0.f);                                       \
        }                                                                   \
    }

__launch_bounds__(128)
__global__ void k_rk(const float* __restrict__ qf, const float* __restrict__ filtp,
                     const float* __restrict__ cw, float* __restrict__ out) {
    __shared__ __align__(16) float fl[300];   // [25 hw][12 pad]
    __shared__ float wsum[2];
    int p = blockIdx.x;
    int bi = p / (NQ * KW); int rem = p % (NQ * KW);
    int q = rem / KW; int k = rem % KW;
    int tid = threadIdx.x;

    // filt logits: elems tid and tid+128, 8 partials each, fully unrolled
    const float* fp0 = filtp + (size_t)p * 8 * 225;
    bool has1 = tid < 97;
    int e1 = has1 ? tid + 128 : tid;
    float a0 = 0.f, a1 = 0.f;
    #pragma unroll
    for (int cs = 0; cs < 8; ++cs) a0 += fp0[cs * 225 + tid];
    #pragma unroll
    for (int cs = 0; cs < 8; ++cs) a1 += fp0[cs * 225 + e1];

    fl[(tid / 9) * 12 + (tid % 9)] = 1.f / (1.f + expf(-a0));
    if (has1) {
        int i2 = tid + 128;
        fl[(i2 / 9) * 12 + (i2 % 9)] = 1.f / (1.f + expf(-a1));
    }
    __syncthreads();

    const float* qbase = qf + ((size_t)(bi * NQ + q)) * C * HW;
    const float* cwb = cw + (size_t)(bi * KW + k) * C;
    float acc5 = 0.f;
    #pragma unroll 1
    for (int ch = 0; ch < 5; ++ch) {
        int c = ch * 128 + tid;
        const float* fq = qbase + (size_t)c * HW;
        float F[25];
        #pragma unroll
        for (int i = 0; i < 25; ++i) F[i] = fq[i];

        float K1[25], K2[25], K3[25], Q[25];
        GSTEP(F, K1);
        #pragma unroll
        for (int i = 0; i < 25; ++i) Q[i] = F[i] + K1[i] * (1.f / 3.f);
        GSTEP(Q, K2);
        #pragma unroll
        for (int i = 0; i < 25; ++i) Q[i] = F[i] + K2[i] - K1[i] * (1.f / 3.f);
        GSTEP(Q, K3);
        #pragma unroll
        for (int i = 0; i < 25; ++i) {
            Q[i] = F[i] + K1[i] - K2[i] + K3[i];
            K1[i] += 3.f * (K2[i] + K3[i]);
        }
        GSTEP(Q, K3);

        float S = 0.f;
        #pragma unroll
        for (int i = 0; i < 25; ++i) S += F[i] + (K1[i] + K3[i]) * 0.125f;
        acc5 = fmaf(cwb[c], S, acc5);
    }

    float val = acc5;
    #pragma unroll
    for (int off = 32; off > 0; off >>= 1) val += __shfl_down(val, off, 64);
    if ((tid & 63) == 0) wsum[tid >> 6] = val;
    __syncthreads();
    if (tid == 0) out[p] = (wsum[0] + wsum[1]) * (1.f / 49.f);
}

extern "C" void kernel_launch(void* const* d_in, const int* in_sizes, int n_in,
                              void* d_out, int out_size, void* d_ws, size_t ws_size,
                              hipStream_t stream) {
    const float* sf    = (const float*)d_in[0];
    const float* qf    = (const float*)d_in[1];
    const float* st    = (const float*)d_in[2];
    const float* w_off = (const float*)d_in[4];
    const float* w_def = (const float*)d_in[5];
    float* out = (float*)d_out;
    float* ws  = (float*)d_ws;
    ushort_t* wmfh = (ushort_t*)(ws + WS_WMFH);
    ushort_t* wdh  = (ushort_t*)(ws + WS_WDH);
    ushort_t* wdl  = (ushort_t*)(ws + WS_WDL);

    k_prep<<<PB_PROTO + PB_WMF + PB_WDF, 256, 0, stream>>>(
        sf, st, w_off, w_def, ws + WS_PROTO, wmfh, wdh, wdl);
    k_off<<<1290, 256, 0, stream>>>(qf, ws + WS_PROTO, wmfh, ws + WS_OFFP, ws + WS_CW);
    k_def<<<dim3(P, 8), 256, 0, stream>>>(ws + WS_PROTO, ws + WS_OFFP, wdh, wdl, ws + WS_FILTP);
    k_rk<<<P, 128, 0, stream>>>(qf, ws + WS_FILTP, ws + WS_CW, out);
}

// Round 18
// 77.773 us; speedup vs baseline: 1.0343x; 1.0343x over previous
//
#include <hip/hip_runtime.h>
#include <math.h>

// Problem constants
#define BB 2      // batch
#define NS 25     // support images
#define NQ 16     // queries
#define KW 5      // n_way
#define C  640
#define HW 25     // 5x5
#define C2 1280
#define P  160    // BB*NQ*KW

typedef unsigned short ushort_t;
typedef unsigned int uint_t;
typedef __attribute__((ext_vector_type(8))) short short8;
typedef __attribute__((ext_vector_type(4))) short short4v;
typedef __attribute__((ext_vector_type(16))) float f32x16;

// Workspace layout (float offsets)
#define WS_PROTO   0          // 160000
#define WS_WDH     160000     // 92160 (184320 ushort)
#define WS_WDL     252160     // 92160
#define WS_CW      344320     // 6400
#define WS_PART    350720     // 800
#define WS_WMFH    351680     // 512000 (1.024M ushort)
#define WS_OFFP    863680     // P*16*450 = 1152000
#define WS_FILTP   2015680    // P*8*225 = 288000 -> end 2303680 (9.2MB)

static __device__ inline ushort_t f2bf(float x) {
    uint_t u = __float_as_uint(x);
    uint_t r = (u + 0x7FFFu + ((u >> 16) & 1u)) >> 16;
    return (ushort_t)r;
}
static __device__ inline float bf2f(ushort_t b) {
    return __uint_as_float(((uint_t)b) << 16);
}

// ---------------- fused prep (branch by block) --------------------------
// blocks 0..124:   proto — thread per (bi,c,hw); each sf value read ONCE,
//                  accumulated into all 5 class sums (bitwise-identical).
// blocks 125..624: w_off -> A-frags (hi only)
// blocks 625..714: w_def -> A-frags (hi/lo)
#define PB_PROTO 125
#define PB_WMF   500
#define PB_WDF   90
__global__ void k_prep(const float* __restrict__ sf, const float* __restrict__ st,
                       const float* __restrict__ w_off, const float* __restrict__ w_def,
                       float* __restrict__ proto, ushort_t* __restrict__ wh,
                       ushort_t* __restrict__ wdh, ushort_t* __restrict__ wdl) {
    int b = blockIdx.x;
    int tid = threadIdx.x;
    if (b < PB_PROTO) {
        __shared__ float stw[250];    // st is (bi,n,k) linear = bi*125+n*5+k
        if (tid < 250) stw[tid] = st[tid];
        __syncthreads();
        int i = b * 256 + tid;        // < 32000 exactly (125*256)
        int bi = i / 16000;
        int e = i - bi * 16000;       // c*25+hw
        const float* sfb = sf + (size_t)bi * NS * 16000 + e;
        int sb = bi * 125;
        float num0 = 0.f, num1 = 0.f, num2 = 0.f, num3 = 0.f, num4 = 0.f;
        float den0 = 0.f, den1 = 0.f, den2 = 0.f, den3 = 0.f, den4 = 0.f;
        for (int n = 0; n < NS; ++n) {
            float v = sfb[(size_t)n * 16000];
            const float* w = &stw[sb + n * 5];
            num0 = fmaf(w[0], v, num0); den0 += w[0];
            num1 = fmaf(w[1], v, num1); den1 += w[1];
            num2 = fmaf(w[2], v, num2); den2 += w[2];
            num3 = fmaf(w[3], v, num3); den3 += w[3];
            num4 = fmaf(w[4], v, num4); den4 += w[4];
        }
        float* pr = proto + (size_t)bi * 5 * 16000 + e;
        pr[0 * 16000] = num0 / den0;
        pr[1 * 16000] = num1 / den1;
        pr[2 * 16000] = num2 / den2;
        pr[3 * 16000] = num3 / den3;
        pr[4 * 16000] = num4 / den4;
    } else if (b < PB_PROTO + PB_WMF) {
        // layout [kc(16)][t(25)][c16(5)][lane(64)][j(8)] = idx*8+j
        // A-frag (32x32x16): row(o)=lane&31, k(c_local)=(lane>>5)*8+j
        int idx = (b - PB_PROTO) * 256 + tid;   // < 128000 exactly
        int lane = idx & 63;
        int r = idx >> 6;
        int c16 = r % 5; r /= 5;
        int t = r % 25;
        int kc = r / 25;
        int o = lane & 31;
        int cb = kc * 80 + c16 * 16 + ((lane >> 5) << 3);
        union { short8 v; ushort_t u[8]; } hs;
        #pragma unroll
        for (int j = 0; j < 8; ++j) {
            float w = (o < 18) ? w_off[((size_t)o * C2 + cb + j) * 25 + t] : 0.f;
            hs.u[j] = f2bf(w);
        }
        *(short8*)(wh + (size_t)idx * 8) = hs.v;
    } else {
        // layout [kc(8)][s(45)][lane(64)][j(8)]; k_lin=s*16+(lane>>5)*8+j
        int idx = (b - PB_PROTO - PB_WMF) * 256 + tid;
        if (idx >= 8 * 45 * 64) return;
        int lane = idx & 63;
        int r = idx >> 6;
        int s = r % 45;
        int kc = r / 45;
        int o = lane & 31;
        int kbase = s * 16 + ((lane >> 5) << 3);
        union { short8 v; ushort_t u[8]; } hs, ls;
        #pragma unroll
        for (int j = 0; j < 8; ++j) {
            int k_lin = kbase + j;
            int c_local = k_lin / 9, kk = k_lin - 9 * c_local;
            float w = (o < 9) ? w_def[((size_t)o * C + kc * 80 + c_local) * 9 + kk] : 0.f;
            ushort_t h = f2bf(w);
            hs.u[j] = h;
            ls.u[j] = f2bf(w - bf2f(h));
        }
        *(short8*)(wdh + (size_t)idx * 8) = hs.v;
        *(short8*)(wdl + (size_t)idx * 8) = ls.v;
    }
}

// ---------------- 5x5 offset conv (MFMA, 1 pass, 2 pairs) + normcw ------
// blocks 0..1279: k_off, g=b>>4 (2 pairs), kc=b&15 (80-ch K-chunk).
// blocks 1280..1289: fused norm+cw for (bi,k) = b-1280.
// Only row 0 (the OOB zero row) is ever read from unwritten space, so only
// that row is zeroed (92 dwords vs 2392).
__launch_bounds__(256)
__attribute__((amdgpu_waves_per_eu(4, 4)))
__global__ void k_off(const float* __restrict__ qf, const float* __restrict__ proto,
                      const ushort_t* __restrict__ wh, float* __restrict__ offp,
                      float* __restrict__ cw) {
    __shared__ __align__(16) float scr[4096];      // 16 KB; B0|B1 alias low 9568 B
    int tid = threadIdx.x;
    if (blockIdx.x >= 1280) {
        // ---- norm + cw for one (bi,k) ----
        float* nr = scr;            // [250]
        float* inv = scr + 256;     // [25]
        int blk = blockIdx.x - 1280;
        const float* base = proto + (size_t)blk * C * HW;
        if (tid < 250) {
            int hw = tid / 10, sl = tid % 10;
            float s = 0.f;
            for (int c = sl; c < C; c += 10) { float v = base[c * HW + hw]; s += v * v; }
            nr[tid] = s;
        }
        __syncthreads();
        if (tid < 25) {
            float s = 0.f;
            #pragma unroll
            for (int j = 0; j < 10; ++j) s += nr[tid * 10 + j];
            inv[tid] = 1.f / fmaxf(sqrtf(s), 1e-12f);
        }
        __syncthreads();
        for (int c = tid; c < C; c += 256) {
            float s = 0.f;
            #pragma unroll
            for (int hw = 0; hw < HW; ++hw) s += base[c * HW + hw] * inv[hw];
            cw[(size_t)blk * C + c] = s * (1.f / 25.f);
        }
        return;
    }
    ushort_t* B0 = (ushort_t*)scr;                 // [26][92]
    ushort_t* B1 = (ushort_t*)scr + 2392;
    int g = blockIdx.x >> 4, kc = blockIdx.x & 15;
    int cbase = kc * 80;
    int lane = tid & 63, wv = tid >> 6;

    // pair source pointers (qf-vs-proto choice is block-uniform)
    int p0 = g * 2, p1 = g * 2 + 1;
    int bi0 = p0 / (NQ * KW), rm0 = p0 % (NQ * KW);
    int bi1 = p1 / (NQ * KW), rm1 = p1 % (NQ * KW);
    const float* src0 = (cbase < C)
        ? qf + ((bi0 * NQ + rm0 / KW) * C + cbase) * HW
        : proto + ((bi0 * KW + rm0 % KW) * C + (cbase - C)) * HW;
    const float* src1 = (cbase < C)
        ? qf + ((bi1 * NQ + rm1 / KW) * C + cbase) * HW
        : proto + ((bi1 * KW + rm1 % KW) * C + (cbase - C)) * HW;

    // batched loads into registers (independent, one waitcnt)
    float v[16];
    #pragma unroll
    for (int r = 0; r < 16; ++r) {
        int i = tid + r * 256;
        int e = min(i, 3999);
        v[r] = (e < 2000) ? src0[e] : src1[e - 2000];
    }

    // zero only the OOB row (row 0 of each pair): 46 dwords each
    if (tid < 92) {
        int j = tid / 46, o = tid - j * 46;
        ((uint_t*)B0)[j * 1196 + o] = 0u;
    }
    __syncthreads();
    #pragma unroll
    for (int r = 0; r < 16; ++r) {
        int i = tid + r * 256;
        if (i < 4000) {
            int j = i / 2000, e = i % 2000;
            int cc = e / 25, pp = e % 25;
            (j ? B1 : B0)[(1 + pp) * 92 + cc] = f2bf(v[r]);
        }
    }
    __syncthreads();

    int hw = lane & 31;
    int by = hw / 5, bx = hw % 5;          // lanes hw>=25 compute junk, never read
    int laneCh = (lane >> 5) * 8;
    const ushort_t* whp = wh + (size_t)kc * 64000 + lane * 8;

    f32x16 acc0, acc1;
    #pragma unroll
    for (int r = 0; r < 16; ++r) { acc0[r] = 0.f; acc1[r] = 0.f; }

    union U8 { short8 v8; short4v v4[2]; };

    for (int t = wv; t < 25; t += 4) {
        int ty = t / 5, tx = t % 5;
        int ry = by + ty - 2, rx = bx + tx - 2;
        bool valid = (ry >= 0 && ry < 5 && rx >= 0 && rx < 5);
        int row = valid ? (1 + ry * 5 + rx) : 0;
        int base0 = row * 92 + laneCh;
        const ushort_t* ahp = whp + (size_t)t * 2560;
        #pragma unroll
        for (int c16 = 0; c16 < 5; ++c16) {
            short8 a_h = *(const short8*)(ahp + c16 * 512);
            U8 b0, b1;
            b0.v4[0] = *(const short4v*)(B0 + base0 + c16 * 16);
            b0.v4[1] = *(const short4v*)(B0 + base0 + c16 * 16 + 4);
            b1.v4[0] = *(const short4v*)(B1 + base0 + c16 * 16);
            b1.v4[1] = *(const short4v*)(B1 + base0 + c16 * 16 + 4);
            acc0 = __builtin_amdgcn_mfma_f32_32x32x16_bf16(a_h, b0.v8, acc0, 0, 0, 0);
            acc1 = __builtin_amdgcn_mfma_f32_32x32x16_bf16(a_h, b1.v8, acc1, 0, 0, 0);
        }
    }

    #define EMIT_PAIR(J, ACC)                                                   \
    {                                                                           \
        __syncthreads();                                                        \
        _Pragma("unroll")                                                       \
        for (int r = 0; r < 16; ++r) scr[r * 256 + tid] = ACC[r];               \
        __syncthreads();                                                        \
        int p = g * 2 + (J);                                                    \
        float* dst = offp + ((size_t)p * 16 + kc) * 450;                        \
        for (int i = tid; i < 450; i += 256) {                                  \
            int o = i / 25, hw2 = i % 25;                                       \
            int r = (o & 3) | ((o >> 3) << 2);                                  \
            int ln = hw2 + ((o >> 2) & 1) * 32;                                 \
            float s = scr[r * 256 + ln] + scr[r * 256 + 64 + ln]                \
                    + scr[r * 256 + 128 + ln] + scr[r * 256 + 192 + ln];        \
            dst[o * 25 + hw2] = s;                                              \
        }                                                                       \
    }
    EMIT_PAIR(0, acc0)
    EMIT_PAIR(1, acc1)
    #undef EMIT_PAIR
}

// ---------------- deformable 3x3 conv via MFMA, C-split 8 ---------------
__launch_bounds__(256)
__global__ void k_def(const float* __restrict__ proto, const float* __restrict__ offp,
                      const ushort_t* __restrict__ wdh, const ushort_t* __restrict__ wdl,
                      float* __restrict__ filtp) {
    __shared__ __align__(16) float plds[2000];        // [80 c][25 hw]
    __shared__ __align__(16) ushort_t samp[25 * 728]; // 36400 B; scr aliases
    int p = blockIdx.x, kc = blockIdx.y;
    int bi = p / (NQ * KW); int rem = p % (NQ * KW);
    int k = rem % KW;
    const float* ftr = proto + ((bi * KW + k) * C + kc * 80) * HW;
    int tid = threadIdx.x, lane = tid & 63, wv = tid >> 6;

    // register-batched staging of plds
    float pv[8];
    #pragma unroll
    for (int r = 0; r < 8; ++r) pv[r] = ftr[min(tid + r * 256, 1999)];
    #pragma unroll
    for (int r = 0; r < 8; ++r) {
        int i = tid + r * 256;
        if (i < 2000) plds[i] = pv[r];
    }
    __syncthreads();

    if (tid < 225) {
        int kk = tid / 25, hw = tid % 25;
        float offY = 0.f, offX = 0.f;
        #pragma unroll
        for (int kcc = 0; kcc < 16; ++kcc) {
            const float* ob = offp + ((size_t)p * 16 + kcc) * 450;
            offY += ob[(kk * 2 + 0) * 25 + hw];
            offX += ob[(kk * 2 + 1) * 25 + hw];
        }
        int h = hw / 5, w = hw % 5, ky = kk / 3, kx = kk % 3;
        float py = (float)(h + ky - 1) + offY;
        float px = (float)(w + kx - 1) + offX;
        float y0f = floorf(py), x0f = floorf(px);
        float ty = py - y0f, tx = px - x0f;
        int y0 = (int)y0f, x0 = (int)x0f;
        int y1 = y0 + 1, x1 = x0 + 1;
        bool vy0 = (y0 >= 0 && y0 < 5), vy1 = (y1 >= 0 && y1 < 5);
        bool vx0 = (x0 >= 0 && x0 < 5), vx1 = (x1 >= 0 && x1 < 5);
        int cy0 = min(max(y0, 0), 4), cy1 = min(max(y1, 0), 4);
        int cx0 = min(max(x0, 0), 4), cx1 = min(max(x1, 0), 4);
        int i0 = cy0 * 5 + cx0, i1 = cy0 * 5 + cx1;
        int i2 = cy1 * 5 + cx0, i3 = cy1 * 5 + cx1;
        float wb0 = (vy0 && vx0) ? (1.f - ty) * (1.f - tx) : 0.f;
        float wb1 = (vy0 && vx1) ? (1.f - ty) * tx : 0.f;
        float wb2 = (vy1 && vx0) ? ty * (1.f - tx) : 0.f;
        float wb3 = (vy1 && vx1) ? ty * tx : 0.f;
        for (int c = 0; c < 80; ++c) {
            const float* base = &plds[c * 25];
            float s = wb0 * base[i0] + wb1 * base[i1] + wb2 * base[i2] + wb3 * base[i3];
            samp[hw * 728 + c * 9 + kk] = f2bf(s);
        }
    }
    __syncthreads();

    int hwr = (lane & 31) < 25 ? (lane & 31) : 0;    // junk cols never read back
    int k8 = (lane >> 5) * 8;
    const ushort_t* ahp = wdh + ((size_t)kc * 45 * 64 + lane) * 8;
    const ushort_t* alp = wdl + ((size_t)kc * 45 * 64 + lane) * 8;

    f32x16 acc;
    #pragma unroll
    for (int r = 0; r < 16; ++r) acc[r] = 0.f;

    for (int s = wv; s < 45; s += 4) {
        short8 b = *(const short8*)(samp + hwr * 728 + s * 16 + k8);
        short8 a_l = *(const short8*)(alp + (size_t)s * 512);
        short8 a_h = *(const short8*)(ahp + (size_t)s * 512);
        acc = __builtin_amdgcn_mfma_f32_32x32x16_bf16(a_l, b, acc, 0, 0, 0);
        acc = __builtin_amdgcn_mfma_f32_32x32x16_bf16(a_h, b, acc, 0, 0, 0);
    }

    __syncthreads();
    float* scr = (float*)samp;    // 16 KB <= 36.4 KB
    #pragma unroll
    for (int r = 0; r < 16; ++r) scr[r * 256 + tid] = acc[r];
    __syncthreads();

    float* dst = filtp + ((size_t)p * 8 + kc) * 225;
    for (int i = tid; i < 225; i += 256) {
        int o = i / 25, hw2 = i % 25;
        int r = (o & 3) | ((o >> 3) << 2);
        int ln = hw2 + ((o >> 2) & 1) * 32;
        float s = scr[r * 256 + ln] + scr[r * 256 + 64 + ln]
                + scr[r * 256 + 128 + ln] + scr[r * 256 + 192 + ln];
        dst[o * 25 + hw2] = s;
    }
}

// ---------------- RK4 + class score — fl padded [25][12], vec reads -----
#define GSTEP(QA, KA)                                                       \
    {                                                                       \
        _Pragma("unroll")                                                   \
        for (int hw_ = 0; hw_ < 25; ++hw_) {                                \
            const int h_ = hw_ / 5, w_ = hw_ % 5;                           \
            float4 fA_ = *(const float4*)&fl[hw_ * 12];                     \
            float4 fB_ = *(const float4*)&fl[hw_ * 12 + 4];                 \
            float f8_ = fl[hw_ * 12 + 8];                                   \
            const float flv_[9] = {fA_.x, fA_.y, fA_.z, fA_.w,              \
                                   fB_.x, fB_.y, fB_.z, fB_.w, f8_};        \
            float s_ = 0.f;                                                 \
            _Pragma("unroll")                                               \
            for (int kp_ = 0; kp_ < 9; ++kp_) {                             \
                const int y_ = h_ + kp_ / 3 - 1, x_ = w_ + kp_ % 3 - 1;     \
                if (y_ >= 0 && y_ < 5 && x_ >= 0 && x_ < 5)                 \
                    s_ = fmaf(QA[y_ * 5 + x_], flv_[kp_], s_);              \
            }                                                               \
            KA[hw_] = fmaxf(s_, 0.f);                                       \
        }                                                                   \
    }

__launch_bounds__(128)
__global__ void k_rk(const float* __restrict__ qf, const float* __restrict__ filtp,
                     const float* __restrict__ cw, float* __restrict__ part) {
    __shared__ __align__(16) float fl[300];   // [25 hw][12 pad]
    __shared__ float wsum[2];
    int bid = blockIdx.x;
    int p = bid / 5, ch = bid % 5;
    int bi = p / (NQ * KW); int rem = p % (NQ * KW);
    int q = rem / KW; int k = rem % KW;
    int tid = threadIdx.x;
    int c = ch * 128 + tid;

    // filt logits: elems tid and tid+128, 8 partials each, fully unrolled
    const float* fp0 = filtp + (size_t)p * 8 * 225;
    bool has1 = tid < 97;
    int e1 = has1 ? tid + 128 : tid;
    float a0 = 0.f, a1 = 0.f;
    #pragma unroll
    for (int cs = 0; cs < 8; ++cs) a0 += fp0[cs * 225 + tid];
    #pragma unroll
    for (int cs = 0; cs < 8; ++cs) a1 += fp0[cs * 225 + e1];

    // F direct from global (25 independent loads, one waitcnt)
    const float* fq = qf + (((size_t)(bi * NQ + q)) * C + c) * HW;
    float F[25];
    #pragma unroll
    for (int i = 0; i < 25; ++i) F[i] = fq[i];

    fl[(tid / 9) * 12 + (tid % 9)] = 1.f / (1.f + expf(-a0));
    if (has1) {
        int i2 = tid + 128;
        fl[(i2 / 9) * 12 + (i2 % 9)] = 1.f / (1.f + expf(-a1));
    }
    __syncthreads();

    float K1[25], K2[25], K3[25], Q[25];
    GSTEP(F, K1);
    #pragma unroll
    for (int i = 0; i < 25; ++i) Q[i] = F[i] + K1[i] * (1.f / 3.f);
    GSTEP(Q, K2);
    #pragma unroll
    for (int i = 0; i < 25; ++i) Q[i] = F[i] + K2[i] - K1[i] * (1.f / 3.f);
    GSTEP(Q, K3);
    #pragma unroll
    for (int i = 0; i < 25; ++i) {
        Q[i] = F[i] + K1[i] - K2[i] + K3[i];
        K1[i] += 3.f * (K2[i] + K3[i]);
    }
    GSTEP(Q, K3);

    float S = 0.f;
    #pragma unroll
    for (int i = 0; i < 25; ++i) S += F[i] + (K1[i] + K3[i]) * 0.125f;

    float val = cw[(bi * KW + k) * C + c] * S;
    #pragma unroll
    for (int off = 32; off > 0; off >>= 1) val += __shfl_down(val, off, 64);
    if ((tid & 63) == 0) wsum[tid >> 6] = val;
    __syncthreads();
    if (tid == 0) part[p * 5 + ch] = wsum[0] + wsum[1];
}

// ---------------- final -------------------------------------------------
__global__ void k_fin(const float* __restrict__ part, float* __restrict__ out) {
    int i = blockIdx.x * 256 + threadIdx.x;
    if (i < P) {
        float s = 0.f;
        #pragma unroll
        for (int ch = 0; ch < 5; ++ch) s += part[i * 5 + ch];
        out[i] = s * (1.f / 49.f);
    }
}

extern "C" void kernel_launch(void* const* d_in, const int* in_sizes, int n_in,
                              void* d_out, int out_size, void* d_ws, size_t ws_size,
                              hipStream_t stream) {
    const float* sf    = (const float*)d_in[0];
    const float* qf    = (const float*)d_in[1];
    const float* st    = (const float*)d_in[2];
    const float* w_off = (const float*)d_in[4];
    const float* w_def = (const float*)d_in[5];
    float* out = (float*)d_out;
    float* ws  = (float*)d_ws;
    ushort_t* wmfh = (ushort_t*)(ws + WS_WMFH);
    ushort_t* wdh  = (ushort_t*)(ws + WS_WDH);
    ushort_t* wdl  = (ushort_t*)(ws + WS_WDL);

    k_prep<<<PB_PROTO + PB_WMF + PB_WDF, 256, 0, stream>>>(
        sf, st, w_off, w_def, ws + WS_PROTO, wmfh, wdh, wdl);
    k_off<<<1290, 256, 0, stream>>>(qf, ws + WS_PROTO, wmfh, ws + WS_OFFP, ws + WS_CW);
    k_def<<<dim3(P, 8), 256, 0, stream>>>(ws + WS_PROTO, ws + WS_OFFP, wdh, wdl, ws + WS_FILTP);
    k_rk<<<P * 5, 128, 0, stream>>>(qf, ws + WS_FILTP, ws + WS_CW, ws + WS_PART);
    k_fin<<<1, 256, 0, stream>>>(ws + WS_PART, out);
}